// Round 1
// baseline (300.380 us; speedup 1.0000x reference)
//
#include <hip/hip_runtime.h>
#include <stdint.h>

#define EMB 1024
#define HEADS 16
#define NB 2
#define NS 2048
#define HD 64
#define NTOK (NB*NS)          // 4096
#define SCALE 0.03125f        // 1/sqrt(1024)
#define LOG2E 1.4426950408889634f

typedef __attribute__((ext_vector_type(8))) short short8;
typedef __attribute__((ext_vector_type(4))) float f32x4;

// round-to-nearest-even f32 -> bf16 bits
__device__ inline unsigned short f2bf(float f) {
  unsigned int x = __builtin_bit_cast(unsigned int, f);
  x += 0x7FFFu + ((x >> 16) & 1u);
  return (unsigned short)(x >> 16);
}

__global__ void cvt_bf16_kernel(const float* __restrict__ s,
                                unsigned short* __restrict__ d, int n) {
  int i = (blockIdx.x * blockDim.x + threadIdx.x) * 8;
  if (i >= n) return;
  float4 v0 = *reinterpret_cast<const float4*>(s + i);
  float4 v1 = *reinterpret_cast<const float4*>(s + i + 4);
  short8 o;
  o[0] = (short)f2bf(v0.x); o[1] = (short)f2bf(v0.y);
  o[2] = (short)f2bf(v0.z); o[3] = (short)f2bf(v0.w);
  o[4] = (short)f2bf(v1.x); o[5] = (short)f2bf(v1.y);
  o[6] = (short)f2bf(v1.z); o[7] = (short)f2bf(v1.w);
  *reinterpret_cast<short8*>(d + i) = o;
}

// C[M][N] = A[M][K] * Bw[N][K]^T + bias[N];  A,Bw bf16 bits, accum f32.
// 128x128 tile, BK=32, 4 waves (2x2), each wave 64x64 = 4x4 frags of 16x16.
template<bool OUT_BF16>
__global__ __launch_bounds__(256) void gemm_bt_kernel(
    const unsigned short* __restrict__ A,
    const unsigned short* __restrict__ Bw,
    const float* __restrict__ bias,
    void* __restrict__ Cout, int M, int N, int K) {
  __shared__ unsigned short As[128 * 32];
  __shared__ unsigned short Bs[128 * 32];
  const int tid = threadIdx.x;
  const int lane = tid & 63;
  const int wave = tid >> 6;
  const int wr = wave >> 1, wc = wave & 1;
  const int g = lane >> 4, r = lane & 15;
  const int brow = blockIdx.y * 128;
  const int bcol = blockIdx.x * 128;

  const f32x4 zf = {0.f, 0.f, 0.f, 0.f};
  f32x4 acc[4][4];
  #pragma unroll
  for (int m = 0; m < 4; ++m)
    #pragma unroll
    for (int n = 0; n < 4; ++n) acc[m][n] = zf;

  for (int k0 = 0; k0 < K; k0 += 32) {
    __syncthreads();
    #pragma unroll
    for (int c = 0; c < 2; ++c) {
      int eo = (c * 256 + tid) * 8;          // element offset in 128x32 tile
      int row = eo >> 5, col = eo & 31;
      *reinterpret_cast<short8*>(&As[eo]) =
          *reinterpret_cast<const short8*>(&A[(size_t)(brow + row) * K + k0 + col]);
      *reinterpret_cast<short8*>(&Bs[eo]) =
          *reinterpret_cast<const short8*>(&Bw[(size_t)(bcol + row) * K + k0 + col]);
    }
    __syncthreads();
    short8 af[4], bfr[4];
    #pragma unroll
    for (int m = 0; m < 4; ++m)
      af[m] = *reinterpret_cast<const short8*>(&As[(wr * 64 + m * 16 + r) * 32 + g * 8]);
    #pragma unroll
    for (int n = 0; n < 4; ++n)
      bfr[n] = *reinterpret_cast<const short8*>(&Bs[(wc * 64 + n * 16 + r) * 32 + g * 8]);
    #pragma unroll
    for (int m = 0; m < 4; ++m)
      #pragma unroll
      for (int n = 0; n < 4; ++n)
        acc[m][n] = __builtin_amdgcn_mfma_f32_16x16x32_bf16(af[m], bfr[n], acc[m][n], 0, 0, 0);
  }

  #pragma unroll
  for (int n = 0; n < 4; ++n) {
    int col = bcol + wc * 64 + n * 16 + r;
    float bv = bias[col];
    #pragma unroll
    for (int m = 0; m < 4; ++m) {
      #pragma unroll
      for (int reg = 0; reg < 4; ++reg) {
        int row = brow + wr * 64 + m * 16 + g * 4 + reg;
        float v = acc[m][n][reg] + bv;
        if (OUT_BF16)
          ((unsigned short*)Cout)[(size_t)row * N + col] = f2bf(v);
        else
          ((float*)Cout)[(size_t)row * N + col] = v;
      }
    }
  }
}

// Flash attention over one contiguous slab [NS][HD], Q=K=V=slab.
// Block = (slab, 64 q-rows); 4 waves x 16 q-rows; KVBLK=32.
__global__ __launch_bounds__(256) void attn_kernel(
    const unsigned short* __restrict__ qb, unsigned short* __restrict__ ob) {
  const int slab = blockIdx.y;
  const int qtile = blockIdx.x;
  const unsigned short* Qs = qb + (size_t)slab * NS * HD;
  unsigned short* Os = ob + (size_t)slab * NS * HD;
  const int tid = threadIdx.x;
  const int lane = tid & 63;
  const int wave = tid >> 6;
  const int g = lane >> 4, r = lane & 15;
  const int qrow0 = qtile * 64 + wave * 16;

  __shared__ unsigned short K_lds[32 * 64];    // row-major [kv][d]
  __shared__ unsigned short Vt_lds[64 * 32];   // transposed [d][kv]
  __shared__ unsigned short P_lds[4][16 * 32]; // per-wave P tile

  // Q fragments (A-operand): row = r, k = kk*32 + g*8 .. +7
  short8 a_q[2];
  #pragma unroll
  for (int kk = 0; kk < 2; ++kk)
    a_q[kk] = *reinterpret_cast<const short8*>(&Qs[(size_t)(qrow0 + r) * HD + kk * 32 + g * 8]);

  const f32x4 zf = {0.f, 0.f, 0.f, 0.f};
  f32x4 o_acc[4];
  float m_run[4], l_run[4];
  #pragma unroll
  for (int i = 0; i < 4; ++i) { o_acc[i] = zf; m_run[i] = -1e30f; l_run[i] = 0.f; }

  for (int kt = 0; kt < NS / 32; ++kt) {
    __syncthreads();
    { // stage K (row-major) and V^T, converting nothing (already bf16)
      int eo = tid * 8;                 // 0..2047 over 32x64 tile
      int row = eo >> 6, col = eo & 63;
      short8 v = *reinterpret_cast<const short8*>(&Qs[(size_t)(kt * 32 + row) * HD + col]);
      *reinterpret_cast<short8*>(&K_lds[eo]) = v;
      #pragma unroll
      for (int j = 0; j < 8; ++j)
        Vt_lds[(col + j) * 32 + row] = (unsigned short)v[j];
    }
    __syncthreads();

    // S = Q * K^T : two 16x16 j-blocks, K=64 via 2 MFMAs each
    f32x4 s[2];
    #pragma unroll
    for (int jb = 0; jb < 2; ++jb) {
      s[jb] = zf;
      #pragma unroll
      for (int kk = 0; kk < 2; ++kk) {
        short8 bk = *reinterpret_cast<const short8*>(
            &K_lds[(jb * 16 + r) * 64 + kk * 32 + g * 8]);
        s[jb] = __builtin_amdgcn_mfma_f32_16x16x32_bf16(a_q[kk], bk, s[jb], 0, 0, 0);
      }
    }
    #pragma unroll
    for (int jb = 0; jb < 2; ++jb)
      #pragma unroll
      for (int reg = 0; reg < 4; ++reg)
        s[jb][reg] *= SCALE;

    // online softmax; rows = g*4+reg, cols spread over 16 lanes x 2 jb
    float p[2][4];
    #pragma unroll
    for (int reg = 0; reg < 4; ++reg) {
      float mt = fmaxf(s[0][reg], s[1][reg]);
      #pragma unroll
      for (int off = 1; off < 16; off <<= 1)
        mt = fmaxf(mt, __shfl_xor(mt, off));
      float m_new = fmaxf(m_run[reg], mt);
      float fac = exp2f((m_run[reg] - m_new) * LOG2E);
      m_run[reg] = m_new;
      float psum = 0.f;
      #pragma unroll
      for (int jb = 0; jb < 2; ++jb) {
        p[jb][reg] = exp2f((s[jb][reg] - m_new) * LOG2E);
        psum += p[jb][reg];
      }
      #pragma unroll
      for (int off = 1; off < 16; off <<= 1)
        psum += __shfl_xor(psum, off);
      l_run[reg] = l_run[reg] * fac + psum;
      #pragma unroll
      for (int n = 0; n < 4; ++n)
        o_acc[n][reg] *= fac;
    }

    // P -> per-wave LDS (transpose to A-frag layout)
    #pragma unroll
    for (int jb = 0; jb < 2; ++jb)
      #pragma unroll
      for (int reg = 0; reg < 4; ++reg)
        P_lds[wave][(g * 4 + reg) * 32 + jb * 16 + r] = f2bf(p[jb][reg]);
    __syncthreads();

    // O += P * V : A = P[16 x 32], B[k][col] = Vt[col][k]
    short8 ap = *reinterpret_cast<const short8*>(&P_lds[wave][r * 32 + g * 8]);
    #pragma unroll
    for (int n = 0; n < 4; ++n) {
      short8 bv = *reinterpret_cast<const short8*>(&Vt_lds[(n * 16 + r) * 32 + g * 8]);
      o_acc[n] = __builtin_amdgcn_mfma_f32_16x16x32_bf16(ap, bv, o_acc[n], 0, 0, 0);
    }
  }

  #pragma unroll
  for (int reg = 0; reg < 4; ++reg) {
    float inv_l = 1.f / l_run[reg];
    #pragma unroll
    for (int n = 0; n < 4; ++n) {
      int row = qrow0 + g * 4 + reg;
      int col = n * 16 + r;
      Os[(size_t)row * HD + col] = f2bf(o_acc[n][reg] * inv_l);
    }
  }
}

extern "C" void kernel_launch(void* const* d_in, const int* in_sizes, int n_in,
                              void* d_out, int out_size, void* d_ws, size_t ws_size,
                              hipStream_t stream) {
  const float* x  = (const float*)d_in[0];
  const float* wq = (const float*)d_in[1];
  const float* bq = (const float*)d_in[2];
  const float* wu = (const float*)d_in[3];
  const float* bu = (const float*)d_in[4];
  float* out = (float*)d_out;

  char* ws = (char*)d_ws;
  unsigned short* xb  = (unsigned short*)(ws);                 // 8 MB
  unsigned short* qb  = (unsigned short*)(ws + (8u  << 20));   // 8 MB
  unsigned short* ob  = (unsigned short*)(ws + (16u << 20));   // 8 MB
  unsigned short* wqb = (unsigned short*)(ws + (24u << 20));   // 2 MB
  unsigned short* wub = (unsigned short*)(ws + (26u << 20));   // 2 MB

  cvt_bf16_kernel<<<(NTOK * EMB / 8 + 255) / 256, 256, 0, stream>>>(x, xb, NTOK * EMB);
  cvt_bf16_kernel<<<(EMB * EMB / 8 + 255) / 256, 256, 0, stream>>>(wq, wqb, EMB * EMB);
  cvt_bf16_kernel<<<(EMB * EMB / 8 + 255) / 256, 256, 0, stream>>>(wu, wub, EMB * EMB);

  // q = x @ wq^T + bq  -> bf16
  gemm_bt_kernel<true><<<dim3(EMB / 128, NTOK / 128), 256, 0, stream>>>(
      xb, wqb, bq, qb, NTOK, EMB, EMB);

  // 32 slabs x 32 q-tiles
  attn_kernel<<<dim3(NS / 64, HEADS * NB), 256, 0, stream>>>(qb, ob);

  // y = O @ wu^T + bu -> f32
  gemm_bt_kernel<false><<<dim3(EMB / 128, NTOK / 128), 256, 0, stream>>>(
      ob, wub, bu, out, NTOK, EMB, EMB);
}

// Round 2
// 169.657 us; speedup vs baseline: 1.7705x; 1.7705x over previous
//
#include <hip/hip_runtime.h>
#include <stdint.h>

#define EMB 1024
#define HEADS 16
#define NB 2
#define NS 2048
#define HD 64
#define NTOK (NB*NS)          // 4096
#define KVBLK 64
#define QW 32                 // q rows per wave
#define QBLK 128              // q rows per block (4 waves)
#define SEXP 0.0450842167f    // (1/32) * log2(e)

typedef __attribute__((ext_vector_type(8))) short short8;
typedef __attribute__((ext_vector_type(4))) float f32x4;

// round-to-nearest-even f32 -> bf16 bits
__device__ inline unsigned short f2bf(float f) {
  unsigned int x = __builtin_bit_cast(unsigned int, f);
  x += 0x7FFFu + ((x >> 16) & 1u);
  return (unsigned short)(x >> 16);
}

__global__ void cvt_bf16_kernel(const float* __restrict__ s,
                                unsigned short* __restrict__ d, int n) {
  int i = (blockIdx.x * blockDim.x + threadIdx.x) * 8;
  if (i >= n) return;
  float4 v0 = *reinterpret_cast<const float4*>(s + i);
  float4 v1 = *reinterpret_cast<const float4*>(s + i + 4);
  short8 o;
  o[0] = (short)f2bf(v0.x); o[1] = (short)f2bf(v0.y);
  o[2] = (short)f2bf(v0.z); o[3] = (short)f2bf(v0.w);
  o[4] = (short)f2bf(v1.x); o[5] = (short)f2bf(v1.y);
  o[6] = (short)f2bf(v1.z); o[7] = (short)f2bf(v1.w);
  *reinterpret_cast<short8*>(d + i) = o;
}

// per-slab transpose: src [32][2048][64] -> dst [32][64][2048]
__global__ __launch_bounds__(256) void transpose_kernel(
    const unsigned short* __restrict__ src, unsigned short* __restrict__ dst) {
  __shared__ unsigned short t[64][72];   // pad: row stride 144B
  const int slab = blockIdx.y, kt = blockIdx.x;
  const unsigned short* s = src + ((size_t)slab * NS + kt * 64) * HD;
  unsigned short* d = dst + (size_t)slab * HD * NS + kt * 64;
  const int tid = threadIdx.x;
  #pragma unroll
  for (int c = 0; c < 2; ++c) {
    int idx = c * 256 + tid;             // 0..511
    int row = idx >> 3, col = (idx & 7) * 8;
    short8 v = *reinterpret_cast<const short8*>(s + row * HD + col);
    *reinterpret_cast<short8*>(&t[row][col]) = v;
  }
  __syncthreads();
  #pragma unroll
  for (int c = 0; c < 2; ++c) {
    int idx = c * 256 + tid;
    int drow = idx >> 3, col = (idx & 7) * 8;  // output row d, kv chunk
    short8 v;
    #pragma unroll
    for (int j = 0; j < 8; ++j) v[j] = t[col + j][drow];
    *reinterpret_cast<short8*>(d + (size_t)drow * NS + col) = v;
  }
}

// C[M][N] = A[M][K] * Bw[N][K]^T + bias[N];  A,Bw bf16 bits, accum f32.
template<bool OUT_BF16>
__global__ __launch_bounds__(256) void gemm_bt_kernel(
    const unsigned short* __restrict__ A,
    const unsigned short* __restrict__ Bw,
    const float* __restrict__ bias,
    void* __restrict__ Cout, int M, int N, int K) {
  __shared__ unsigned short As[128 * 32];
  __shared__ unsigned short Bs[128 * 32];
  const int tid = threadIdx.x;
  const int lane = tid & 63;
  const int wave = tid >> 6;
  const int wr = wave >> 1, wc = wave & 1;
  const int g = lane >> 4, r = lane & 15;
  const int brow = blockIdx.y * 128;
  const int bcol = blockIdx.x * 128;

  const f32x4 zf = {0.f, 0.f, 0.f, 0.f};
  f32x4 acc[4][4];
  #pragma unroll
  for (int m = 0; m < 4; ++m)
    #pragma unroll
    for (int n = 0; n < 4; ++n) acc[m][n] = zf;

  for (int k0 = 0; k0 < K; k0 += 32) {
    __syncthreads();
    #pragma unroll
    for (int c = 0; c < 2; ++c) {
      int eo = (c * 256 + tid) * 8;
      int row = eo >> 5, col = eo & 31;
      *reinterpret_cast<short8*>(&As[eo]) =
          *reinterpret_cast<const short8*>(&A[(size_t)(brow + row) * K + k0 + col]);
      *reinterpret_cast<short8*>(&Bs[eo]) =
          *reinterpret_cast<const short8*>(&Bw[(size_t)(bcol + row) * K + k0 + col]);
    }
    __syncthreads();
    short8 af[4], bfr[4];
    #pragma unroll
    for (int m = 0; m < 4; ++m)
      af[m] = *reinterpret_cast<const short8*>(&As[(wr * 64 + m * 16 + r) * 32 + g * 8]);
    #pragma unroll
    for (int n = 0; n < 4; ++n)
      bfr[n] = *reinterpret_cast<const short8*>(&Bs[(wc * 64 + n * 16 + r) * 32 + g * 8]);
    #pragma unroll
    for (int m = 0; m < 4; ++m)
      #pragma unroll
      for (int n = 0; n < 4; ++n)
        acc[m][n] = __builtin_amdgcn_mfma_f32_16x16x32_bf16(af[m], bfr[n], acc[m][n], 0, 0, 0);
  }

  #pragma unroll
  for (int n = 0; n < 4; ++n) {
    int col = bcol + wc * 64 + n * 16 + r;
    float bv = bias[col];
    #pragma unroll
    for (int m = 0; m < 4; ++m) {
      #pragma unroll
      for (int reg = 0; reg < 4; ++reg) {
        int row = brow + wr * 64 + m * 16 + g * 4 + reg;
        float v = acc[m][n][reg] + bv;
        if (OUT_BF16)
          ((unsigned short*)Cout)[(size_t)row * N + col] = f2bf(v);
        else
          ((float*)Cout)[(size_t)row * N + col] = v;
      }
    }
  }
}

// Flash attention, Q=K=V = contiguous slab [NS][HD] of qb; Vt pre-transposed.
// Block = (slab, 128 q-rows); 4 waves x 32 q-rows; KVBLK=64; no-max softmax.
__global__ __launch_bounds__(256) void attn_kernel(
    const unsigned short* __restrict__ qb,
    const unsigned short* __restrict__ vtb,
    unsigned short* __restrict__ ob) {
  const int slab = blockIdx.y;
  const int qtile = blockIdx.x;
  const unsigned short* Qs = qb + (size_t)slab * NS * HD;
  const unsigned short* Vts = vtb + (size_t)slab * HD * NS;  // [64][2048]
  unsigned short* Os = ob + (size_t)slab * NS * HD;
  const int tid = threadIdx.x;
  const int lane = tid & 63;
  const int wave = tid >> 6;
  const int g = lane >> 4, r = lane & 15;
  const int qrow0 = qtile * QBLK + wave * QW;
  const int rkey = (r & 7) << 4;   // read-side swizzle key (row&7 == r&7 for our rows)

  __shared__ unsigned short K_lds[2][KVBLK * HD];   // swizzled [kv][64]
  __shared__ unsigned short Vt_lds[2][HD * KVBLK];  // swizzled [d][64]
  __shared__ unsigned short P_lds[4][QW * KVBLK];   // per-wave, swizzled [32][64]
  char* Kb = (char*)&K_lds[0][0];
  char* Vb = (char*)&Vt_lds[0][0];
  char* Pb = (char*)&P_lds[wave][0];

  // Q fragments: A[row=q][k=d], row = m*16+r, k = kk*32+g*8..+7
  short8 aq[2][2];
  #pragma unroll
  for (int m = 0; m < 2; ++m)
    #pragma unroll
    for (int kk = 0; kk < 2; ++kk)
      aq[m][kk] = *reinterpret_cast<const short8*>(
          &Qs[(size_t)(qrow0 + m * 16 + r) * HD + kk * 32 + g * 8]);

  const f32x4 zf = {0.f, 0.f, 0.f, 0.f};
  f32x4 o_acc[2][4];
  float l_part[2][4];
  #pragma unroll
  for (int m = 0; m < 2; ++m)
    #pragma unroll
    for (int n = 0; n < 4; ++n) o_acc[m][n] = zf;
  #pragma unroll
  for (int m = 0; m < 2; ++m)
    #pragma unroll
    for (int q = 0; q < 4; ++q) l_part[m][q] = 0.f;

  auto stage = [&](int bb, int kt) {
    const unsigned short* kp = Qs + (size_t)kt * KVBLK * HD;  // contiguous 8KB
    #pragma unroll
    for (int c = 0; c < 2; ++c) {
      int idx = c * 256 + tid;
      int row = idx >> 3;
      int colb = (idx & 7) << 4;
      short8 v = *reinterpret_cast<const short8*>(kp + idx * 8);
      *reinterpret_cast<short8*>(Kb + bb * (KVBLK * HD * 2) + row * 128 +
                                 (colb ^ ((row & 7) << 4))) = v;
    }
    #pragma unroll
    for (int c = 0; c < 2; ++c) {
      int idx = c * 256 + tid;
      int drow = idx >> 3;
      int colb = (idx & 7) << 4;
      short8 v = *reinterpret_cast<const short8*>(
          Vts + (size_t)drow * NS + kt * KVBLK + ((idx & 7) << 3));
      *reinterpret_cast<short8*>(Vb + bb * (HD * KVBLK * 2) + drow * 128 +
                                 (colb ^ ((drow & 7) << 4))) = v;
    }
  };

  stage(0, 0);
  int cur = 0;
  for (int kt = 0; kt < NS / KVBLK; ++kt) {
    __syncthreads();
    if (kt + 1 < NS / KVBLK) stage(cur ^ 1, kt + 1);
    const char* Kc = Kb + cur * (KVBLK * HD * 2);
    const char* Vc = Vb + cur * (HD * KVBLK * 2);

    // S = Q K^T : s[m][jb], kv col = jb*16+r, q row = g*4+reg (+m*16)
    f32x4 s[2][4];
    #pragma unroll
    for (int jb = 0; jb < 4; ++jb) {
      short8 bk[2];
      #pragma unroll
      for (int kk = 0; kk < 2; ++kk)
        bk[kk] = *reinterpret_cast<const short8*>(
            Kc + (jb * 16 + r) * 128 + ((kk * 64 + g * 16) ^ rkey));
      #pragma unroll
      for (int m = 0; m < 2; ++m) {
        s[m][jb] = zf;
        #pragma unroll
        for (int kk = 0; kk < 2; ++kk)
          s[m][jb] = __builtin_amdgcn_mfma_f32_16x16x32_bf16(aq[m][kk], bk[kk], s[m][jb], 0, 0, 0);
      }
    }

    // no-max softmax: p = exp2(s * SEXP); accumulate row-sum per-lane
    #pragma unroll
    for (int m = 0; m < 2; ++m) {
      #pragma unroll
      for (int reg = 0; reg < 4; ++reg) {
        int prow = m * 16 + g * 4 + reg;
        int pkey = (prow & 7) << 4;
        float p0 = exp2f(s[m][0][reg] * SEXP);
        float p1 = exp2f(s[m][1][reg] * SEXP);
        float p2 = exp2f(s[m][2][reg] * SEXP);
        float p3 = exp2f(s[m][3][reg] * SEXP);
        l_part[m][reg] += (p0 + p1) + (p2 + p3);
        *(unsigned short*)(Pb + prow * 128 + ((0 * 32 + r * 2) ^ pkey)) = f2bf(p0);
        *(unsigned short*)(Pb + prow * 128 + ((1 * 32 + r * 2) ^ pkey)) = f2bf(p1);
        *(unsigned short*)(Pb + prow * 128 + ((2 * 32 + r * 2) ^ pkey)) = f2bf(p2);
        *(unsigned short*)(Pb + prow * 128 + ((3 * 32 + r * 2) ^ pkey)) = f2bf(p3);
      }
    }
    // P_lds is wave-private: drain ds_writes, no block barrier needed
    asm volatile("s_waitcnt lgkmcnt(0)" ::: "memory");

    // O += P V : A[row=q][k=kv] from P_lds, B[k=kv][col=d] from Vt_lds
    short8 ap[2][2];
    #pragma unroll
    for (int m = 0; m < 2; ++m)
      #pragma unroll
      for (int kk = 0; kk < 2; ++kk)
        ap[m][kk] = *reinterpret_cast<const short8*>(
            Pb + (m * 16 + r) * 128 + ((kk * 64 + g * 16) ^ rkey));
    #pragma unroll
    for (int n = 0; n < 4; ++n) {
      short8 bv[2];
      #pragma unroll
      for (int kk = 0; kk < 2; ++kk)
        bv[kk] = *reinterpret_cast<const short8*>(
            Vc + (n * 16 + r) * 128 + ((kk * 64 + g * 16) ^ rkey));
      #pragma unroll
      for (int m = 0; m < 2; ++m)
        #pragma unroll
        for (int kk = 0; kk < 2; ++kk)
          o_acc[m][n] = __builtin_amdgcn_mfma_f32_16x16x32_bf16(ap[m][kk], bv[kk], o_acc[m][n], 0, 0, 0);
    }
    cur ^= 1;
  }

  // epilogue: reduce l over the 16 r-lanes holding each q-row, write O
  #pragma unroll
  for (int m = 0; m < 2; ++m) {
    #pragma unroll
    for (int reg = 0; reg < 4; ++reg) {
      float l = l_part[m][reg];
      #pragma unroll
      for (int off = 1; off < 16; off <<= 1)
        l += __shfl_xor(l, off);
      float inv = 1.f / l;
      int row = qrow0 + m * 16 + g * 4 + reg;
      #pragma unroll
      for (int n = 0; n < 4; ++n)
        Os[(size_t)row * HD + n * 16 + r] = f2bf(o_acc[m][n][reg] * inv);
    }
  }
}

extern "C" void kernel_launch(void* const* d_in, const int* in_sizes, int n_in,
                              void* d_out, int out_size, void* d_ws, size_t ws_size,
                              hipStream_t stream) {
  const float* x  = (const float*)d_in[0];
  const float* wq = (const float*)d_in[1];
  const float* bq = (const float*)d_in[2];
  const float* wu = (const float*)d_in[3];
  const float* bu = (const float*)d_in[4];
  float* out = (float*)d_out;

  char* ws = (char*)d_ws;
  unsigned short* xb  = (unsigned short*)(ws);                 // 8 MB (reused as vtb)
  unsigned short* qb  = (unsigned short*)(ws + (8u  << 20));   // 8 MB
  unsigned short* ob  = (unsigned short*)(ws + (16u << 20));   // 8 MB
  unsigned short* wqb = (unsigned short*)(ws + (24u << 20));   // 2 MB
  unsigned short* wub = (unsigned short*)(ws + (26u << 20));   // 2 MB

  cvt_bf16_kernel<<<(NTOK * EMB / 8 + 255) / 256, 256, 0, stream>>>(x, xb, NTOK * EMB);
  cvt_bf16_kernel<<<(EMB * EMB / 8 + 255) / 256, 256, 0, stream>>>(wq, wqb, EMB * EMB);
  cvt_bf16_kernel<<<(EMB * EMB / 8 + 255) / 256, 256, 0, stream>>>(wu, wub, EMB * EMB);

  // q = x @ wq^T + bq  -> bf16
  gemm_bt_kernel<true><<<dim3(EMB / 128, NTOK / 128), 256, 0, stream>>>(
      xb, wqb, bq, qb, NTOK, EMB, EMB);

  // xb is dead now; reuse as vtb: per-slab transpose of qb
  unsigned short* vtb = xb;
  transpose_kernel<<<dim3(NS / 64, HEADS * NB), 256, 0, stream>>>(qb, vtb);

  // 16 q-tiles x 32 slabs
  attn_kernel<<<dim3(NS / QBLK, HEADS * NB), 256, 0, stream>>>(qb, vtb, ob);

  // y = O @ wu^T + bu -> f32
  gemm_bt_kernel<false><<<dim3(EMB / 128, NTOK / 128), 256, 0, stream>>>(
      ob, wub, bu, out, NTOK, EMB, EMB);
}

// Round 3
// 125.562 us; speedup vs baseline: 2.3923x; 1.3512x over previous
//
#include <hip/hip_runtime.h>
#include <stdint.h>

#define EMB 1024
#define HEADS 16
#define NB 2
#define NS 2048
#define HD 64
#define NTOK (NB*NS)          // 4096
#define KVBLK 64
#define QW 32                 // q rows per wave
#define QBLK 128              // q rows per block (4 waves)
#define SEXP 0.0450842167f    // (1/32) * log2(e)

typedef __attribute__((ext_vector_type(8))) short short8;
typedef __attribute__((ext_vector_type(4))) float f32x4;

// round-to-nearest-even f32 -> bf16 bits (epilogues / cvt only)
__device__ inline unsigned short f2bf(float f) {
  unsigned int x = __builtin_bit_cast(unsigned int, f);
  x += 0x7FFFu + ((x >> 16) & 1u);
  return (unsigned short)(x >> 16);
}

// HW packed f32x2 -> bf16x2 (RNE); no builtin on gfx950 (T12 recipe)
__device__ inline unsigned cvt_pk_bf16(float lo, float hi) {
  unsigned d;
  asm("v_cvt_pk_bf16_f32 %0, %1, %2" : "=v"(d) : "v"(lo), "v"(hi));
  return d;
}

// async global->LDS, 16B per lane; lds dest = wave-uniform base + lane*16
__device__ inline void gld16(const void* g, void* l) {
  __builtin_amdgcn_global_load_lds(
      (const __attribute__((address_space(1))) unsigned int*)g,
      (__attribute__((address_space(3))) unsigned int*)l, 16, 0, 0);
}

__global__ void cvt_bf16_kernel(const float* __restrict__ s,
                                unsigned short* __restrict__ d, int n) {
  int i = (blockIdx.x * blockDim.x + threadIdx.x) * 8;
  if (i >= n) return;
  float4 v0 = *reinterpret_cast<const float4*>(s + i);
  float4 v1 = *reinterpret_cast<const float4*>(s + i + 4);
  short8 o;
  o[0] = (short)f2bf(v0.x); o[1] = (short)f2bf(v0.y);
  o[2] = (short)f2bf(v0.z); o[3] = (short)f2bf(v0.w);
  o[4] = (short)f2bf(v1.x); o[5] = (short)f2bf(v1.y);
  o[6] = (short)f2bf(v1.z); o[7] = (short)f2bf(v1.w);
  *reinterpret_cast<short8*>(d + i) = o;
}

// per-slab transpose: src [32][2048][64] -> dst [32][64][2048], with the
// kv index PERMUTED within each 64-tile: out pos p holds orig kv inv_pi(p),
// inv_pi(p) = (p&3)*16 + (p>>2)  (matches P-store pi(jb*16+r) = r*4+jb).
__global__ __launch_bounds__(256) void transpose_kernel(
    const unsigned short* __restrict__ src, unsigned short* __restrict__ dst) {
  __shared__ unsigned short t[64][72];   // pad: row stride 144B
  const int slab = blockIdx.y, kt = blockIdx.x;
  const unsigned short* s = src + ((size_t)slab * NS + kt * 64) * HD;
  unsigned short* d = dst + (size_t)slab * HD * NS + kt * 64;
  const int tid = threadIdx.x;
  #pragma unroll
  for (int c = 0; c < 2; ++c) {
    int idx = c * 256 + tid;             // 0..511
    int row = idx >> 3, col = (idx & 7) * 8;
    short8 v = *reinterpret_cast<const short8*>(s + row * HD + col);
    *reinterpret_cast<short8*>(&t[row][col]) = v;
  }
  __syncthreads();
  #pragma unroll
  for (int c = 0; c < 2; ++c) {
    int idx = c * 256 + tid;
    int drow = idx >> 3, col = (idx & 7) * 8;
    short8 v;
    #pragma unroll
    for (int j = 0; j < 8; ++j) {
      int p = col + j;
      v[j] = t[(p & 3) * 16 + (p >> 2)][drow];
    }
    *reinterpret_cast<short8*>(d + (size_t)drow * NS + col) = v;
  }
}

// C[M][N] = A[M][K] * Bw[N][K]^T + bias[N].  BM=64 BN=128 BK=64, dbuf,
// global_load_lds staging (linear dest + inverse-swizzled source), 2-phase.
template<bool OUT_BF16>
__global__ __launch_bounds__(256) void gemm_bt_kernel(
    const unsigned short* __restrict__ A,
    const unsigned short* __restrict__ Bw,
    const float* __restrict__ bias,
    void* __restrict__ Cout, int M, int N, int K) {
  __shared__ __align__(16) unsigned short As[2][64 * 64];
  __shared__ __align__(16) unsigned short Bs[2][128 * 64];
  const int tid = threadIdx.x;
  const int lane = tid & 63;
  const int wave = tid >> 6;
  const int wr = wave >> 1, wc = wave & 1;
  const int g = lane >> 4, r = lane & 15;
  const int brow = blockIdx.y * 64;
  const int bcol = blockIdx.x * 128;

  const f32x4 zf = {0.f, 0.f, 0.f, 0.f};
  f32x4 acc[2][4];
  #pragma unroll
  for (int m = 0; m < 2; ++m)
    #pragma unroll
    for (int n = 0; n < 4; ++n) acc[m][n] = zf;

  auto stage = [&](int bb, int k0) {
    #pragma unroll
    for (int i = 0; i < 2; ++i) {            // A: 64x64 = 8KB = 2 issues
      int base = i * 4096 + wave * 1024;
      int L = base + lane * 16;
      int row = L >> 7, lsl = ((L >> 4) & 7) ^ (row & 7);
      gld16((const char*)A + ((size_t)(brow + row) * K + k0) * 2 + lsl * 16,
            (char*)&As[bb][0] + base);
    }
    #pragma unroll
    for (int i = 0; i < 4; ++i) {            // B: 128x64 = 16KB = 4 issues
      int base = i * 4096 + wave * 1024;
      int L = base + lane * 16;
      int row = L >> 7, lsl = ((L >> 4) & 7) ^ (row & 7);
      gld16((const char*)Bw + ((size_t)(bcol + row) * K + k0) * 2 + lsl * 16,
            (char*)&Bs[bb][0] + base);
    }
  };

  stage(0, 0);
  int cur = 0;
  for (int k0 = 0; k0 < K; k0 += 64) {
    __syncthreads();                          // drains prev stage (vmcnt)
    if (k0 + 64 < K) stage(cur ^ 1, k0 + 64);
    const char* Ac = (const char*)&As[cur][0];
    const char* Bc = (const char*)&Bs[cur][0];
    short8 af[2][2], bfr[4][2];
    #pragma unroll
    for (int m = 0; m < 2; ++m) {
      int row = wr * 32 + m * 16 + r;
      #pragma unroll
      for (int kk = 0; kk < 2; ++kk)
        af[m][kk] = *reinterpret_cast<const short8*>(
            Ac + row * 128 + ((kk * 64 + g * 16) ^ ((row & 7) << 4)));
    }
    #pragma unroll
    for (int n = 0; n < 4; ++n) {
      int row = wc * 64 + n * 16 + r;
      #pragma unroll
      for (int kk = 0; kk < 2; ++kk)
        bfr[n][kk] = *reinterpret_cast<const short8*>(
            Bc + row * 128 + ((kk * 64 + g * 16) ^ ((row & 7) << 4)));
    }
    #pragma unroll
    for (int kk = 0; kk < 2; ++kk)
      #pragma unroll
      for (int m = 0; m < 2; ++m)
        #pragma unroll
        for (int n = 0; n < 4; ++n)
          acc[m][n] = __builtin_amdgcn_mfma_f32_16x16x32_bf16(af[m][kk], bfr[n][kk], acc[m][n], 0, 0, 0);
    cur ^= 1;
  }

  #pragma unroll
  for (int n = 0; n < 4; ++n) {
    int col = bcol + wc * 64 + n * 16 + r;
    float bv = bias[col];
    #pragma unroll
    for (int m = 0; m < 2; ++m) {
      #pragma unroll
      for (int reg = 0; reg < 4; ++reg) {
        int row = brow + wr * 32 + m * 16 + g * 4 + reg;
        float v = acc[m][n][reg] + bv;
        if (OUT_BF16)
          ((unsigned short*)Cout)[(size_t)row * N + col] = f2bf(v);
        else
          ((float*)Cout)[(size_t)row * N + col] = v;
      }
    }
  }
}

// Flash attention, Q=K=V = contiguous slab [NS][HD]; Vt pre-transposed and
// pi-permuted. 4 waves x 32 q-rows; KVBLK=64; no-max softmax; P via pi-packed
// ds_write_b64; K/V staged with global_load_lds (async across the iteration).
__global__ __launch_bounds__(256) void attn_kernel(
    const unsigned short* __restrict__ qb,
    const unsigned short* __restrict__ vtb,
    unsigned short* __restrict__ ob) {
  const int slab = blockIdx.y;
  const int qtile = blockIdx.x;
  const unsigned short* Qs = qb + (size_t)slab * NS * HD;
  const unsigned short* Vts = vtb + (size_t)slab * HD * NS;  // [64][2048] permuted
  unsigned short* Os = ob + (size_t)slab * NS * HD;
  const int tid = threadIdx.x;
  const int lane = tid & 63;
  const int wave = tid >> 6;
  const int g = lane >> 4, r = lane & 15;
  const int qrow0 = qtile * QBLK + wave * QW;
  const int rkey = (r & 7) << 4;

  __shared__ __align__(16) unsigned short K_lds[2][KVBLK * HD];   // [kv][64] swz
  __shared__ __align__(16) unsigned short Vt_lds[2][HD * KVBLK];  // [d][pi-kv] swz
  __shared__ __align__(16) unsigned short P_lds[4][QW * KVBLK];   // [q][pi-kv] swz
  char* Pb = (char*)&P_lds[wave][0];

  auto stage = [&](int bb, int kt) {
    const char* Kg = (const char*)(Qs + (size_t)kt * KVBLK * HD);  // 8KB tile
    const char* Vg = (const char*)Vts + (size_t)kt * 128;          // col offset
    #pragma unroll
    for (int i = 0; i < 2; ++i) {
      int base = i * 4096 + wave * 1024;
      int L = base + lane * 16;
      int row = L >> 7, lsl = ((L >> 4) & 7) ^ (row & 7);
      gld16(Kg + row * 128 + lsl * 16, (char*)&K_lds[bb][0] + base);
      gld16(Vg + (size_t)row * (NS * 2) + lsl * 16, (char*)&Vt_lds[bb][0] + base);
    }
  };

  // Q fragments: A[row=q][k=d], row = m*16+r, k = kk*32 + g*8..+7
  short8 aq[2][2];
  #pragma unroll
  for (int m = 0; m < 2; ++m)
    #pragma unroll
    for (int kk = 0; kk < 2; ++kk)
      aq[m][kk] = *reinterpret_cast<const short8*>(
          &Qs[(size_t)(qrow0 + m * 16 + r) * HD + kk * 32 + g * 8]);

  const f32x4 zf = {0.f, 0.f, 0.f, 0.f};
  f32x4 o_acc[2][4];
  float l_part[2][4];
  #pragma unroll
  for (int m = 0; m < 2; ++m)
    #pragma unroll
    for (int n = 0; n < 4; ++n) o_acc[m][n] = zf;
  #pragma unroll
  for (int m = 0; m < 2; ++m)
    #pragma unroll
    for (int q = 0; q < 4; ++q) l_part[m][q] = 0.f;

  stage(0, 0);
  int cur = 0;
  for (int kt = 0; kt < NS / KVBLK; ++kt) {
    __syncthreads();                          // drains this buffer's loads
    if (kt + 1 < NS / KVBLK) stage(cur ^ 1, kt + 1);
    const char* Kc = (const char*)&K_lds[cur][0];
    const char* Vc = (const char*)&Vt_lds[cur][0];

    // S = Q K^T : kv col = jb*16+r (orig order), q row = m*16+g*4+reg
    f32x4 s[2][4];
    #pragma unroll
    for (int jb = 0; jb < 4; ++jb) {
      short8 bk[2];
      #pragma unroll
      for (int kk = 0; kk < 2; ++kk)
        bk[kk] = *reinterpret_cast<const short8*>(
            Kc + (jb * 16 + r) * 128 + ((kk * 64 + g * 16) ^ rkey));
      #pragma unroll
      for (int m = 0; m < 2; ++m) {
        s[m][jb] = zf;
        #pragma unroll
        for (int kk = 0; kk < 2; ++kk)
          s[m][jb] = __builtin_amdgcn_mfma_f32_16x16x32_bf16(aq[m][kk], bk[kk], s[m][jb], 0, 0, 0);
      }
    }

    // no-max softmax; pack 4 P-values per row into pi positions r*4..r*4+3
    #pragma unroll
    for (int m = 0; m < 2; ++m) {
      #pragma unroll
      for (int reg = 0; reg < 4; ++reg) {
        int prow = m * 16 + g * 4 + reg;
        float p0 = exp2f(s[m][0][reg] * SEXP);
        float p1 = exp2f(s[m][1][reg] * SEXP);
        float p2 = exp2f(s[m][2][reg] * SEXP);
        float p3 = exp2f(s[m][3][reg] * SEXP);
        l_part[m][reg] += (p0 + p1) + (p2 + p3);
        uint2 w;
        w.x = cvt_pk_bf16(p0, p1);
        w.y = cvt_pk_bf16(p2, p3);
        *reinterpret_cast<uint2*>(
            Pb + prow * 128 + ((r * 8) ^ ((prow & 7) << 4))) = w;
      }
    }
    // P_lds is wave-private: drain ds_writes only (not the async vm stage)
    asm volatile("s_waitcnt lgkmcnt(0)" ::: "memory");

    // O += P V, both in pi order: k = pi-pos kk*32+g*8..+7
    short8 ap[2][2];
    #pragma unroll
    for (int m = 0; m < 2; ++m)
      #pragma unroll
      for (int kk = 0; kk < 2; ++kk)
        ap[m][kk] = *reinterpret_cast<const short8*>(
            Pb + (m * 16 + r) * 128 + ((kk * 64 + g * 16) ^ rkey));
    #pragma unroll
    for (int n = 0; n < 4; ++n) {
      short8 bv[2];
      #pragma unroll
      for (int kk = 0; kk < 2; ++kk)
        bv[kk] = *reinterpret_cast<const short8*>(
            Vc + (n * 16 + r) * 128 + ((kk * 64 + g * 16) ^ rkey));
      #pragma unroll
      for (int m = 0; m < 2; ++m)
        #pragma unroll
        for (int kk = 0; kk < 2; ++kk)
          o_acc[m][n] = __builtin_amdgcn_mfma_f32_16x16x32_bf16(ap[m][kk], bv[kk], o_acc[m][n], 0, 0, 0);
    }
    cur ^= 1;
  }

  // epilogue: reduce l over the 16 r-lanes holding each q-row, write O
  #pragma unroll
  for (int m = 0; m < 2; ++m) {
    #pragma unroll
    for (int reg = 0; reg < 4; ++reg) {
      float l = l_part[m][reg];
      #pragma unroll
      for (int off = 1; off < 16; off <<= 1)
        l += __shfl_xor(l, off);
      float inv = 1.f / l;
      int row = qrow0 + m * 16 + g * 4 + reg;
      #pragma unroll
      for (int n = 0; n < 4; ++n)
        Os[(size_t)row * HD + n * 16 + r] = f2bf(o_acc[m][n][reg] * inv);
    }
  }
}

extern "C" void kernel_launch(void* const* d_in, const int* in_sizes, int n_in,
                              void* d_out, int out_size, void* d_ws, size_t ws_size,
                              hipStream_t stream) {
  const float* x  = (const float*)d_in[0];
  const float* wq = (const float*)d_in[1];
  const float* bq = (const float*)d_in[2];
  const float* wu = (const float*)d_in[3];
  const float* bu = (const float*)d_in[4];
  float* out = (float*)d_out;

  char* ws = (char*)d_ws;
  unsigned short* xb  = (unsigned short*)(ws);                 // 8 MB (reused as vtb)
  unsigned short* qb  = (unsigned short*)(ws + (8u  << 20));   // 8 MB
  unsigned short* ob  = (unsigned short*)(ws + (16u << 20));   // 8 MB
  unsigned short* wqb = (unsigned short*)(ws + (24u << 20));   // 2 MB
  unsigned short* wub = (unsigned short*)(ws + (26u << 20));   // 2 MB

  cvt_bf16_kernel<<<(NTOK * EMB / 8 + 255) / 256, 256, 0, stream>>>(x, xb, NTOK * EMB);
  cvt_bf16_kernel<<<(EMB * EMB / 8 + 255) / 256, 256, 0, stream>>>(wq, wqb, EMB * EMB);
  cvt_bf16_kernel<<<(EMB * EMB / 8 + 255) / 256, 256, 0, stream>>>(wu, wub, EMB * EMB);

  // q = x @ wq^T + bq  -> bf16
  gemm_bt_kernel<true><<<dim3(EMB / 128, NTOK / 64), 256, 0, stream>>>(
      xb, wqb, bq, qb, NTOK, EMB, EMB);

  // xb is dead now; reuse as vtb: per-slab pi-permuted transpose of qb
  unsigned short* vtb = xb;
  transpose_kernel<<<dim3(NS / 64, HEADS * NB), 256, 0, stream>>>(qb, vtb);

  // 16 q-tiles x 32 slabs
  attn_kernel<<<dim3(NS / QBLK, HEADS * NB), 256, 0, stream>>>(qb, vtb, ob);

  // y = O @ wu^T + bu -> f32
  gemm_bt_kernel<false><<<dim3(EMB / 128, NTOK / 64), 256, 0, stream>>>(
      ob, wub, bu, out, NTOK, EMB, EMB);
}

// Round 6
// 109.187 us; speedup vs baseline: 2.7511x; 1.1500x over previous
//
#include <hip/hip_runtime.h>
#include <stdint.h>

#define EMB 1024
#define HEADS 16
#define NB 2
#define NS 2048
#define HD 64
#define NTOK (NB*NS)          // 4096
#define KVBLK 64
#define QW 32                 // q rows per wave
#define QBLK 128              // q rows per block (4 waves)
#define SEXP2 0.04508421676368185f   // log2(e)/32, folded into prescaled Q

typedef __attribute__((ext_vector_type(8))) short short8;
typedef __attribute__((ext_vector_type(4))) float f32x4;

// round-to-nearest-even f32 -> bf16 bits (epilogues / cvt only)
__device__ inline unsigned short f2bf(float f) {
  unsigned int x = __builtin_bit_cast(unsigned int, f);
  x += 0x7FFFu + ((x >> 16) & 1u);
  return (unsigned short)(x >> 16);
}

// HW packed f32x2 -> bf16x2 (RNE); no builtin on gfx950 (T12 recipe)
__device__ inline unsigned cvt_pk_bf16(float lo, float hi) {
  unsigned d;
  asm("v_cvt_pk_bf16_f32 %0, %1, %2" : "=v"(d) : "v"(lo), "v"(hi));
  return d;
}

// async global->LDS, 16B per lane; lds dest = wave-uniform base + lane*16
__device__ inline void gld16(const void* g, void* l) {
  __builtin_amdgcn_global_load_lds(
      (const __attribute__((address_space(1))) unsigned int*)g,
      (__attribute__((address_space(3))) unsigned int*)l, 16, 0, 0);
}

__global__ void cvt_bf16_kernel(const float* __restrict__ s,
                                unsigned short* __restrict__ d, int n) {
  int i = (blockIdx.x * blockDim.x + threadIdx.x) * 8;
  if (i >= n) return;
  float4 v0 = *reinterpret_cast<const float4*>(s + i);
  float4 v1 = *reinterpret_cast<const float4*>(s + i + 4);
  short8 o;
  o[0] = (short)f2bf(v0.x); o[1] = (short)f2bf(v0.y);
  o[2] = (short)f2bf(v0.z); o[3] = (short)f2bf(v0.w);
  o[4] = (short)f2bf(v1.x); o[5] = (short)f2bf(v1.y);
  o[6] = (short)f2bf(v1.z); o[7] = (short)f2bf(v1.w);
  *reinterpret_cast<short8*>(d + i) = o;
}

// per-slab transpose: src [32][2048][64] -> dst [32][64][2048], with the
// kv index PERMUTED within each 64-tile: out pos p holds orig kv inv_pi(p),
// inv_pi(p) = (p&3)*16 + (p>>2)  (matches P-store pi(jb*16+r) = r*4+jb).
__global__ __launch_bounds__(256) void transpose_kernel(
    const unsigned short* __restrict__ src, unsigned short* __restrict__ dst) {
  __shared__ unsigned short t[64][72];   // pad: row stride 144B
  const int slab = blockIdx.y, kt = blockIdx.x;
  const unsigned short* s = src + ((size_t)slab * NS + kt * 64) * HD;
  unsigned short* d = dst + (size_t)slab * HD * NS + kt * 64;
  const int tid = threadIdx.x;
  #pragma unroll
  for (int c = 0; c < 2; ++c) {
    int idx = c * 256 + tid;             // 0..511
    int row = idx >> 3, col = (idx & 7) * 8;
    short8 v = *reinterpret_cast<const short8*>(s + row * HD + col);
    *reinterpret_cast<short8*>(&t[row][col]) = v;
  }
  __syncthreads();
  #pragma unroll
  for (int c = 0; c < 2; ++c) {
    int idx = c * 256 + tid;
    int drow = idx >> 3, col = (idx & 7) * 8;
    short8 v;
    #pragma unroll
    for (int j = 0; j < 8; ++j) {
      int p = col + j;
      v[j] = t[(p & 3) * 16 + (p >> 2)][drow];
    }
    *reinterpret_cast<short8*>(d + (size_t)drow * NS + col) = v;
  }
}

// C[M][N] = A[M][K] * Bw[N][K]^T + bias[N].  BM=64 BN=128 BK=64, dbuf,
// global_load_lds staging (linear dest + inverse-swizzled source), 2-phase.
// Optional second output: Qscaled = bf16((C)*SEXP2), single-rounded.
template<bool OUT_BF16>
__global__ __launch_bounds__(256) void gemm_bt_kernel(
    const unsigned short* __restrict__ A,
    const unsigned short* __restrict__ Bw,
    const float* __restrict__ bias,
    void* __restrict__ Cout,
    unsigned short* __restrict__ Qscaled,
    int M, int N, int K) {
  __shared__ __align__(16) unsigned short As[2][64 * 64];
  __shared__ __align__(16) unsigned short Bs[2][128 * 64];
  const int tid = threadIdx.x;
  const int lane = tid & 63;
  const int wave = tid >> 6;
  const int wr = wave >> 1, wc = wave & 1;
  const int g = lane >> 4, r = lane & 15;
  const int brow = blockIdx.y * 64;
  const int bcol = blockIdx.x * 128;

  const f32x4 zf = {0.f, 0.f, 0.f, 0.f};
  f32x4 acc[2][4];
  #pragma unroll
  for (int m = 0; m < 2; ++m)
    #pragma unroll
    for (int n = 0; n < 4; ++n) acc[m][n] = zf;

  auto stage = [&](int bb, int k0) {
    #pragma unroll
    for (int i = 0; i < 2; ++i) {            // A: 64x64 = 8KB = 2 issues
      int base = i * 4096 + wave * 1024;
      int L = base + lane * 16;
      int row = L >> 7, lsl = ((L >> 4) & 7) ^ (row & 7);
      gld16((const char*)A + ((size_t)(brow + row) * K + k0) * 2 + lsl * 16,
            (char*)&As[bb][0] + base);
    }
    #pragma unroll
    for (int i = 0; i < 4; ++i) {            // B: 128x64 = 16KB = 4 issues
      int base = i * 4096 + wave * 1024;
      int L = base + lane * 16;
      int row = L >> 7, lsl = ((L >> 4) & 7) ^ (row & 7);
      gld16((const char*)Bw + ((size_t)(bcol + row) * K + k0) * 2 + lsl * 16,
            (char*)&Bs[bb][0] + base);
    }
  };

  stage(0, 0);
  int cur = 0;
  for (int k0 = 0; k0 < K; k0 += 64) {
    __syncthreads();                          // drains prev stage (vmcnt)
    if (k0 + 64 < K) stage(cur ^ 1, k0 + 64);
    const char* Ac = (const char*)&As[cur][0];
    const char* Bc = (const char*)&Bs[cur][0];
    short8 af[2][2], bfr[4][2];
    #pragma unroll
    for (int m = 0; m < 2; ++m) {
      int row = wr * 32 + m * 16 + r;
      #pragma unroll
      for (int kk = 0; kk < 2; ++kk)
        af[m][kk] = *reinterpret_cast<const short8*>(
            Ac + row * 128 + ((kk * 64 + g * 16) ^ ((row & 7) << 4)));
    }
    #pragma unroll
    for (int n = 0; n < 4; ++n) {
      int row = wc * 64 + n * 16 + r;
      #pragma unroll
      for (int kk = 0; kk < 2; ++kk)
        bfr[n][kk] = *reinterpret_cast<const short8*>(
            Bc + row * 128 + ((kk * 64 + g * 16) ^ ((row & 7) << 4)));
    }
    #pragma unroll
    for (int kk = 0; kk < 2; ++kk)
      #pragma unroll
      for (int m = 0; m < 2; ++m)
        #pragma unroll
        for (int n = 0; n < 4; ++n)
          acc[m][n] = __builtin_amdgcn_mfma_f32_16x16x32_bf16(af[m][kk], bfr[n][kk], acc[m][n], 0, 0, 0);
    cur ^= 1;
  }

  #pragma unroll
  for (int n = 0; n < 4; ++n) {
    int col = bcol + wc * 64 + n * 16 + r;
    float bv = bias[col];
    #pragma unroll
    for (int m = 0; m < 2; ++m) {
      #pragma unroll
      for (int reg = 0; reg < 4; ++reg) {
        int row = brow + wr * 32 + m * 16 + g * 4 + reg;
        float v = acc[m][n][reg] + bv;
        if (OUT_BF16)
          ((unsigned short*)Cout)[(size_t)row * N + col] = f2bf(v);
        else
          ((float*)Cout)[(size_t)row * N + col] = v;
        if (Qscaled)
          Qscaled[(size_t)row * N + col] = f2bf(v * SEXP2);
      }
    }
  }
}

// Flash attention, Q=K=V = contiguous slab [NS][HD]; Vt pre-transposed and
// pi-permuted. 4 waves x 32 q-rows; KVBLK=64; no-max softmax (exp arg folded
// into prescaled Q buffer, single-rounded); l in f32 per-lane partials
// (R3-verified path); raw v_exp_f32; async K/V staging via global_load_lds.
__global__ __launch_bounds__(256) void attn_kernel(
    const unsigned short* __restrict__ qb,
    const unsigned short* __restrict__ qsb,
    const unsigned short* __restrict__ vtb,
    unsigned short* __restrict__ ob) {
  const int slab = blockIdx.y;
  const int qtile = blockIdx.x;
  const unsigned short* Qs = qb + (size_t)slab * NS * HD;
  const unsigned short* Qss = qsb + (size_t)slab * NS * HD;  // prescaled
  const unsigned short* Vts = vtb + (size_t)slab * HD * NS;  // [64][2048] permuted
  unsigned short* Os = ob + (size_t)slab * NS * HD;
  const int tid = threadIdx.x;
  const int lane = tid & 63;
  const int wave = tid >> 6;
  const int g = lane >> 4, r = lane & 15;
  const int qrow0 = qtile * QBLK + wave * QW;
  const int rkey = (r & 7) << 4;

  __shared__ __align__(16) unsigned short K_lds[2][KVBLK * HD];   // [kv][64] swz
  __shared__ __align__(16) unsigned short Vt_lds[2][HD * KVBLK];  // [d][pi-kv] swz
  __shared__ __align__(16) unsigned short P_lds[4][QW * KVBLK];   // [q][pi-kv] swz
  char* Pb = (char*)&P_lds[wave][0];

  auto stage = [&](int bb, int kt) {
    const char* Kg = (const char*)(Qs + (size_t)kt * KVBLK * HD);  // 8KB tile
    const char* Vg = (const char*)Vts + (size_t)kt * 128;          // col offset
    #pragma unroll
    for (int i = 0; i < 2; ++i) {
      int base = i * 4096 + wave * 1024;
      int L = base + lane * 16;
      int row = L >> 7, lsl = ((L >> 4) & 7) ^ (row & 7);
      gld16(Kg + row * 128 + lsl * 16, (char*)&K_lds[bb][0] + base);
      gld16(Vg + (size_t)row * (NS * 2) + lsl * 16, (char*)&Vt_lds[bb][0] + base);
    }
  };

  // Q fragments from the prescaled buffer (single rounding, zero VALU here):
  // A[row=q][k=d], row = m*16+r, k = kk*32 + g*8..+7
  short8 aq[2][2];
  #pragma unroll
  for (int m = 0; m < 2; ++m)
    #pragma unroll
    for (int kk = 0; kk < 2; ++kk)
      aq[m][kk] = *reinterpret_cast<const short8*>(
          &Qss[(size_t)(qrow0 + m * 16 + r) * HD + kk * 32 + g * 8]);

  const f32x4 zf = {0.f, 0.f, 0.f, 0.f};
  f32x4 o_acc[2][4];
  float l_part[2][4];
  #pragma unroll
  for (int m = 0; m < 2; ++m) {
    #pragma unroll
    for (int n = 0; n < 4; ++n) o_acc[m][n] = zf;
    #pragma unroll
    for (int q = 0; q < 4; ++q) l_part[m][q] = 0.f;
  }

  stage(0, 0);
  int cur = 0;
  for (int kt = 0; kt < NS / KVBLK; ++kt) {
    __syncthreads();                          // drains this buffer's loads
    if (kt + 1 < NS / KVBLK) stage(cur ^ 1, kt + 1);
    const char* Kc = (const char*)&K_lds[cur][0];
    const char* Vc = (const char*)&Vt_lds[cur][0];

    // S' = (Q*log2e/32) K^T : kv col = jb*16+r, q row = m*16+g*4+reg
    f32x4 s[2][4];
    #pragma unroll
    for (int jb = 0; jb < 4; ++jb) {
      short8 bk[2];
      #pragma unroll
      for (int kk = 0; kk < 2; ++kk)
        bk[kk] = *reinterpret_cast<const short8*>(
            Kc + (jb * 16 + r) * 128 + ((kk * 64 + g * 16) ^ rkey));
      #pragma unroll
      for (int m = 0; m < 2; ++m) {
        s[m][jb] = zf;
        #pragma unroll
        for (int kk = 0; kk < 2; ++kk)
          s[m][jb] = __builtin_amdgcn_mfma_f32_16x16x32_bf16(aq[m][kk], bk[kk], s[m][jb], 0, 0, 0);
      }
    }

    // p = 2^(s'); f32 row-sum partials; pack 4 P per row into pi positions
    #pragma unroll
    for (int m = 0; m < 2; ++m) {
      #pragma unroll
      for (int reg = 0; reg < 4; ++reg) {
        int prow = m * 16 + g * 4 + reg;
        float p0 = __builtin_amdgcn_exp2f(s[m][0][reg]);
        float p1 = __builtin_amdgcn_exp2f(s[m][1][reg]);
        float p2 = __builtin_amdgcn_exp2f(s[m][2][reg]);
        float p3 = __builtin_amdgcn_exp2f(s[m][3][reg]);
        l_part[m][reg] += (p0 + p1) + (p2 + p3);
        uint2 w;
        w.x = cvt_pk_bf16(p0, p1);
        w.y = cvt_pk_bf16(p2, p3);
        *reinterpret_cast<uint2*>(
            Pb + prow * 128 + ((r * 8) ^ ((prow & 7) << 4))) = w;
      }
    }
    // P_lds is wave-private: drain ds_writes only (not the async vm stage)
    asm volatile("s_waitcnt lgkmcnt(0)" ::: "memory");

    // O += P V (pi order): k = pi-pos kk*32+g*8..+7
    short8 ap[2][2];
    #pragma unroll
    for (int m = 0; m < 2; ++m)
      #pragma unroll
      for (int kk = 0; kk < 2; ++kk)
        ap[m][kk] = *reinterpret_cast<const short8*>(
            Pb + (m * 16 + r) * 128 + ((kk * 64 + g * 16) ^ rkey));
    #pragma unroll
    for (int n = 0; n < 4; ++n) {
      short8 bv[2];
      #pragma unroll
      for (int kk = 0; kk < 2; ++kk)
        bv[kk] = *reinterpret_cast<const short8*>(
            Vc + (n * 16 + r) * 128 + ((kk * 64 + g * 16) ^ rkey));
      #pragma unroll
      for (int m = 0; m < 2; ++m)
        #pragma unroll
        for (int kk = 0; kk < 2; ++kk)
          o_acc[m][n] = __builtin_amdgcn_mfma_f32_16x16x32_bf16(ap[m][kk], bv[kk], o_acc[m][n], 0, 0, 0);
    }
    cur ^= 1;
  }

  // epilogue: reduce l over the 16 r-lanes holding each q-row, write O
  #pragma unroll
  for (int m = 0; m < 2; ++m) {
    #pragma unroll
    for (int reg = 0; reg < 4; ++reg) {
      float l = l_part[m][reg];
      #pragma unroll
      for (int off = 1; off < 16; off <<= 1)
        l += __shfl_xor(l, off);
      float inv = 1.f / l;
      int row = qrow0 + m * 16 + g * 4 + reg;
      #pragma unroll
      for (int n = 0; n < 4; ++n)
        Os[(size_t)row * HD + n * 16 + r] = f2bf(o_acc[m][n][reg] * inv);
    }
  }
}

extern "C" void kernel_launch(void* const* d_in, const int* in_sizes, int n_in,
                              void* d_out, int out_size, void* d_ws, size_t ws_size,
                              hipStream_t stream) {
  const float* x  = (const float*)d_in[0];
  const float* wq = (const float*)d_in[1];
  const float* bq = (const float*)d_in[2];
  const float* wu = (const float*)d_in[3];
  const float* bu = (const float*)d_in[4];
  float* out = (float*)d_out;

  char* ws = (char*)d_ws;
  unsigned short* xb  = (unsigned short*)(ws);                 // 8 MB (reused as vtb)
  unsigned short* qb  = (unsigned short*)(ws + (8u  << 20));   // 8 MB
  unsigned short* ob  = (unsigned short*)(ws + (16u << 20));   // 8 MB (qsb then O)
  unsigned short* wqb = (unsigned short*)(ws + (24u << 20));   // 2 MB
  unsigned short* wub = (unsigned short*)(ws + (26u << 20));   // 2 MB

  cvt_bf16_kernel<<<(NTOK * EMB / 8 + 255) / 256, 256, 0, stream>>>(x, xb, NTOK * EMB);
  cvt_bf16_kernel<<<(EMB * EMB / 8 + 255) / 256, 256, 0, stream>>>(wq, wqb, EMB * EMB);
  cvt_bf16_kernel<<<(EMB * EMB / 8 + 255) / 256, 256, 0, stream>>>(wu, wub, EMB * EMB);

  // q = x @ wq^T + bq -> qb (bf16) and qsb = bf16(q * SEXP2) (single-rounded)
  unsigned short* qsb = ob;   // alias: each attn block reads only its own
                              // q-rows, then writes exactly those rows as O
  gemm_bt_kernel<true><<<dim3(EMB / 128, NTOK / 64), 256, 0, stream>>>(
      xb, wqb, bq, qb, qsb, NTOK, EMB, EMB);

  // xb is dead now; reuse as vtb: per-slab pi-permuted transpose of qb
  unsigned short* vtb = xb;
  transpose_kernel<<<dim3(NS / 64, HEADS * NB), 256, 0, stream>>>(qb, vtb);

  // 16 q-tiles x 32 slabs
  attn_kernel<<<dim3(NS / QBLK, HEADS * NB), 256, 0, stream>>>(qb, qsb, vtb, ob);

  // y = O @ wu^T + bu -> f32
  gemm_bt_kernel<false><<<dim3(EMB / 128, NTOK / 64), 256, 0, stream>>>(
      ob, wub, bu, out, (unsigned short*)nullptr, NTOK, EMB, EMB);
}

// Round 7
// 108.662 us; speedup vs baseline: 2.7644x; 1.0048x over previous
//
#include <hip/hip_runtime.h>
#include <stdint.h>

#define EMB 1024
#define HEADS 16
#define NB 2
#define NS 2048
#define HD 64
#define NTOK (NB*NS)          // 4096
#define KVBLK 64
#define QW 32                 // q rows per wave
#define QBLK 128              // q rows per block (4 waves)
#define SEXP2 0.04508421676368185f   // log2(e)/32, folded into prescaled Q

typedef __attribute__((ext_vector_type(8))) short short8;
typedef __attribute__((ext_vector_type(4))) float f32x4;
typedef __attribute__((ext_vector_type(4))) unsigned int u32x4;

// round-to-nearest-even f32 -> bf16 bits (epilogues / cvt only)
__device__ inline unsigned short f2bf(float f) {
  unsigned int x = __builtin_bit_cast(unsigned int, f);
  x += 0x7FFFu + ((x >> 16) & 1u);
  return (unsigned short)(x >> 16);
}

// HW packed f32x2 -> bf16x2 (RNE); no builtin on gfx950 (T12 recipe)
__device__ inline unsigned cvt_pk_bf16(float lo, float hi) {
  unsigned d;
  asm("v_cvt_pk_bf16_f32 %0, %1, %2" : "=v"(d) : "v"(lo), "v"(hi));
  return d;
}

// async global->LDS, 16B per lane; lds dest = wave-uniform base + lane*16
__device__ inline void gld16(const void* g, void* l) {
  __builtin_amdgcn_global_load_lds(
      (const __attribute__((address_space(1))) unsigned int*)g,
      (__attribute__((address_space(3))) unsigned int*)l, 16, 0, 0);
}

__global__ void cvt_bf16_kernel(const float* __restrict__ s,
                                unsigned short* __restrict__ d, int n) {
  int i = (blockIdx.x * blockDim.x + threadIdx.x) * 8;
  if (i >= n) return;
  float4 v0 = *reinterpret_cast<const float4*>(s + i);
  float4 v1 = *reinterpret_cast<const float4*>(s + i + 4);
  short8 o;
  o[0] = (short)f2bf(v0.x); o[1] = (short)f2bf(v0.y);
  o[2] = (short)f2bf(v0.z); o[3] = (short)f2bf(v0.w);
  o[4] = (short)f2bf(v1.x); o[5] = (short)f2bf(v1.y);
  o[6] = (short)f2bf(v1.z); o[7] = (short)f2bf(v1.w);
  *reinterpret_cast<short8*>(d + i) = o;
}

// per-slab transpose: src [32][2048][64] -> dst [32][64][2048], with the
// kv index PERMUTED within each 64-tile by invpi (matches in-register P
// packing of the swapped-QK^T path):
//   pv position p = kk*32 + g*8 + j  holds  kv = kk*32 + (j>>2)*16 + g*4 + (j&3)
//   invpi(p) = (p&32) | (((p>>2)&1)<<4) | (((p>>3)&3)<<2) | (p&3)
__global__ __launch_bounds__(256) void transpose_kernel(
    const unsigned short* __restrict__ src, unsigned short* __restrict__ dst) {
  __shared__ unsigned short t[64][72];   // pad: row stride 144B
  const int slab = blockIdx.y, kt = blockIdx.x;
  const unsigned short* s = src + ((size_t)slab * NS + kt * 64) * HD;
  unsigned short* d = dst + (size_t)slab * HD * NS + kt * 64;
  const int tid = threadIdx.x;
  #pragma unroll
  for (int c = 0; c < 2; ++c) {
    int idx = c * 256 + tid;             // 0..511
    int row = idx >> 3, col = (idx & 7) * 8;
    short8 v = *reinterpret_cast<const short8*>(s + row * HD + col);
    *reinterpret_cast<short8*>(&t[row][col]) = v;
  }
  __syncthreads();
  #pragma unroll
  for (int c = 0; c < 2; ++c) {
    int idx = c * 256 + tid;
    int drow = idx >> 3, col = (idx & 7) * 8;
    short8 v;
    #pragma unroll
    for (int j = 0; j < 8; ++j) {
      int p = col + j;
      int kv = (p & 32) | (((p >> 2) & 1) << 4) | (((p >> 3) & 3) << 2) | (p & 3);
      v[j] = t[kv][drow];
    }
    *reinterpret_cast<short8*>(d + (size_t)drow * NS + col) = v;
  }
}

// C[M][N] = A[M][K] * Bw[N][K]^T + bias[N].  BM=64 BN=128 BK=64, dbuf,
// global_load_lds staging (linear dest + inverse-swizzled source), 2-phase.
// Optional second output: Qscaled = bf16((C)*SEXP2), single-rounded.
template<bool OUT_BF16>
__global__ __launch_bounds__(256) void gemm_bt_kernel(
    const unsigned short* __restrict__ A,
    const unsigned short* __restrict__ Bw,
    const float* __restrict__ bias,
    void* __restrict__ Cout,
    unsigned short* __restrict__ Qscaled,
    int M, int N, int K) {
  __shared__ __align__(16) unsigned short As[2][64 * 64];
  __shared__ __align__(16) unsigned short Bs[2][128 * 64];
  const int tid = threadIdx.x;
  const int lane = tid & 63;
  const int wave = tid >> 6;
  const int wr = wave >> 1, wc = wave & 1;
  const int g = lane >> 4, r = lane & 15;
  const int brow = blockIdx.y * 64;
  const int bcol = blockIdx.x * 128;

  const f32x4 zf = {0.f, 0.f, 0.f, 0.f};
  f32x4 acc[2][4];
  #pragma unroll
  for (int m = 0; m < 2; ++m)
    #pragma unroll
    for (int n = 0; n < 4; ++n) acc[m][n] = zf;

  auto stage = [&](int bb, int k0) {
    #pragma unroll
    for (int i = 0; i < 2; ++i) {            // A: 64x64 = 8KB = 2 issues
      int base = i * 4096 + wave * 1024;
      int L = base + lane * 16;
      int row = L >> 7, lsl = ((L >> 4) & 7) ^ (row & 7);
      gld16((const char*)A + ((size_t)(brow + row) * K + k0) * 2 + lsl * 16,
            (char*)&As[bb][0] + base);
    }
    #pragma unroll
    for (int i = 0; i < 4; ++i) {            // B: 128x64 = 16KB = 4 issues
      int base = i * 4096 + wave * 1024;
      int L = base + lane * 16;
      int row = L >> 7, lsl = ((L >> 4) & 7) ^ (row & 7);
      gld16((const char*)Bw + ((size_t)(bcol + row) * K + k0) * 2 + lsl * 16,
            (char*)&Bs[bb][0] + base);
    }
  };

  stage(0, 0);
  int cur = 0;
  for (int k0 = 0; k0 < K; k0 += 64) {
    __syncthreads();                          // drains prev stage (vmcnt)
    if (k0 + 64 < K) stage(cur ^ 1, k0 + 64);
    const char* Ac = (const char*)&As[cur][0];
    const char* Bc = (const char*)&Bs[cur][0];
    short8 af[2][2], bfr[4][2];
    #pragma unroll
    for (int m = 0; m < 2; ++m) {
      int row = wr * 32 + m * 16 + r;
      #pragma unroll
      for (int kk = 0; kk < 2; ++kk)
        af[m][kk] = *reinterpret_cast<const short8*>(
            Ac + row * 128 + ((kk * 64 + g * 16) ^ ((row & 7) << 4)));
    }
    #pragma unroll
    for (int n = 0; n < 4; ++n) {
      int row = wc * 64 + n * 16 + r;
      #pragma unroll
      for (int kk = 0; kk < 2; ++kk)
        bfr[n][kk] = *reinterpret_cast<const short8*>(
            Bc + row * 128 + ((kk * 64 + g * 16) ^ ((row & 7) << 4)));
    }
    #pragma unroll
    for (int kk = 0; kk < 2; ++kk)
      #pragma unroll
      for (int m = 0; m < 2; ++m)
        #pragma unroll
        for (int n = 0; n < 4; ++n)
          acc[m][n] = __builtin_amdgcn_mfma_f32_16x16x32_bf16(af[m][kk], bfr[n][kk], acc[m][n], 0, 0, 0);
    cur ^= 1;
  }

  #pragma unroll
  for (int n = 0; n < 4; ++n) {
    int col = bcol + wc * 64 + n * 16 + r;
    float bv = bias[col];
    #pragma unroll
    for (int m = 0; m < 2; ++m) {
      #pragma unroll
      for (int reg = 0; reg < 4; ++reg) {
        int row = brow + wr * 32 + m * 16 + g * 4 + reg;
        float v = acc[m][n][reg] + bv;
        if (OUT_BF16)
          ((unsigned short*)Cout)[(size_t)row * N + col] = f2bf(v);
        else
          ((float*)Cout)[(size_t)row * N + col] = v;
        if (Qscaled)
          Qscaled[(size_t)row * N + col] = f2bf(v * SEXP2);
      }
    }
  }
}

// Flash attention, Q=K=V = contiguous slab [NS][HD]; Vt pre-transposed and
// pi-permuted. 4 waves x 32 q-rows; KVBLK=64; no-max softmax (prescaled Q);
// SWAPPED QK^T (mfma(K,Q)) so each lane holds P for one q-row -> P packs
// in-register for PV (no P LDS round-trip). l = per-lane f32 scalar.
// Grid: 1-D 512 with slab-grouped XCD swizzle.
__global__ __launch_bounds__(256) void attn_kernel(
    const unsigned short* __restrict__ qb,
    const unsigned short* __restrict__ qsb,
    const unsigned short* __restrict__ vtb,
    unsigned short* __restrict__ ob) {
  const int bid = blockIdx.x;            // 0..511
  // XCD k (= bid&7 under round-robin dispatch) owns slabs 4k..4k+3, so each
  // slab's 512KB K/V panel stays in one XCD's L2.
  const int xcd = bid & 7, idx = bid >> 3;
  const int slab = xcd * 4 + (idx >> 4);
  const int qtile = idx & 15;
  const unsigned short* Qs = qb + (size_t)slab * NS * HD;
  const unsigned short* Qss = qsb + (size_t)slab * NS * HD;  // prescaled
  const unsigned short* Vts = vtb + (size_t)slab * HD * NS;  // [64][2048] pi-perm
  unsigned short* Os = ob + (size_t)slab * NS * HD;
  const int tid = threadIdx.x;
  const int lane = tid & 63;
  const int wave = tid >> 6;
  const int g = lane >> 4, r = lane & 15;
  const int qrow0 = qtile * QBLK + wave * QW;
  const int rkey = (r & 7) << 4;

  __shared__ __align__(16) unsigned short K_lds[2][KVBLK * HD];   // [kv][64] swz
  __shared__ __align__(16) unsigned short Vt_lds[2][HD * KVBLK];  // [d][pi-kv] swz

  auto stage = [&](int bb, int kt) {
    const char* Kg = (const char*)(Qs + (size_t)kt * KVBLK * HD);  // 8KB tile
    const char* Vg = (const char*)Vts + (size_t)kt * 128;          // col offset
    #pragma unroll
    for (int i = 0; i < 2; ++i) {
      int base = i * 4096 + wave * 1024;
      int L = base + lane * 16;
      int row = L >> 7, lsl = ((L >> 4) & 7) ^ (row & 7);
      gld16(Kg + row * 128 + lsl * 16, (char*)&K_lds[bb][0] + base);
      gld16(Vg + (size_t)row * (NS * 2) + lsl * 16, (char*)&Vt_lds[bb][0] + base);
    }
  };

  // Q fragments from the prescaled buffer; used as the B operand of the
  // swapped QK^T (B-frag layout == A-frag layout here): col=q row=m*16+r,
  // k = kk*32 + g*8..+7
  short8 aq[2][2];
  #pragma unroll
  for (int m = 0; m < 2; ++m)
    #pragma unroll
    for (int kk = 0; kk < 2; ++kk)
      aq[m][kk] = *reinterpret_cast<const short8*>(
          &Qss[(size_t)(qrow0 + m * 16 + r) * HD + kk * 32 + g * 8]);

  const f32x4 zf = {0.f, 0.f, 0.f, 0.f};
  f32x4 o_acc[2][4];
  float l_lane[2] = {0.f, 0.f};          // q row = r (per lane), per m-block
  #pragma unroll
  for (int m = 0; m < 2; ++m)
    #pragma unroll
    for (int n = 0; n < 4; ++n) o_acc[m][n] = zf;

  stage(0, 0);
  int cur = 0;
  for (int kt = 0; kt < NS / KVBLK; ++kt) {
    __syncthreads();                          // drains this buffer's loads
    if (kt + 1 < NS / KVBLK) stage(cur ^ 1, kt + 1);
    const char* Kc = (const char*)&K_lds[cur][0];
    const char* Vc = (const char*)&Vt_lds[cur][0];

    // S^T = K Q^T : lane(g,r) gets S[kv=jb*16+g*4+reg][q=m*16+r]
    f32x4 s[2][4];
    #pragma unroll
    for (int jb = 0; jb < 4; ++jb) {
      short8 bk[2];
      #pragma unroll
      for (int kk = 0; kk < 2; ++kk)
        bk[kk] = *reinterpret_cast<const short8*>(
            Kc + (jb * 16 + r) * 128 + ((kk * 64 + g * 16) ^ rkey));
      #pragma unroll
      for (int m = 0; m < 2; ++m) {
        s[m][jb] = zf;
        #pragma unroll
        for (int kk = 0; kk < 2; ++kk)
          s[m][jb] = __builtin_amdgcn_mfma_f32_16x16x32_bf16(bk[kk], aq[m][kk], s[m][jb], 0, 0, 0);
      }
    }

    // p = 2^(s); row-sum into per-lane l; pack PV A-frags in-register:
    // ap[m][kk][j] = P[q=r][kv = kk*32 + (j>>2)*16 + g*4 + (j&3)]
    short8 ap[2][2];
    #pragma unroll
    for (int m = 0; m < 2; ++m) {
      float p[4][4];
      #pragma unroll
      for (int jb = 0; jb < 4; ++jb)
        #pragma unroll
        for (int reg = 0; reg < 4; ++reg)
          p[jb][reg] = __builtin_amdgcn_exp2f(s[m][jb][reg]);
      float t0 = (p[0][0] + p[0][1]) + (p[0][2] + p[0][3]);
      float t1 = (p[1][0] + p[1][1]) + (p[1][2] + p[1][3]);
      float t2 = (p[2][0] + p[2][1]) + (p[2][2] + p[2][3]);
      float t3 = (p[3][0] + p[3][1]) + (p[3][2] + p[3][3]);
      l_lane[m] += (t0 + t1) + (t2 + t3);
      #pragma unroll
      for (int kk = 0; kk < 2; ++kk) {
        u32x4 w;
        w.x = cvt_pk_bf16(p[2 * kk][0], p[2 * kk][1]);
        w.y = cvt_pk_bf16(p[2 * kk][2], p[2 * kk][3]);
        w.z = cvt_pk_bf16(p[2 * kk + 1][0], p[2 * kk + 1][1]);
        w.w = cvt_pk_bf16(p[2 * kk + 1][2], p[2 * kk + 1][3]);
        ap[m][kk] = __builtin_bit_cast(short8, w);
      }
    }

    // O += P V (pi order): B[k_pv][col=d] from Vt_lds rows n*16+r
    #pragma unroll
    for (int n = 0; n < 4; ++n) {
      short8 bv[2];
      #pragma unroll
      for (int kk = 0; kk < 2; ++kk)
        bv[kk] = *reinterpret_cast<const short8*>(
            Vc + (n * 16 + r) * 128 + ((kk * 64 + g * 16) ^ rkey));
      #pragma unroll
      for (int m = 0; m < 2; ++m)
        #pragma unroll
        for (int kk = 0; kk < 2; ++kk)
          o_acc[m][n] = __builtin_amdgcn_mfma_f32_16x16x32_bf16(ap[m][kk], bv[kk], o_acc[m][n], 0, 0, 0);
    }
    cur ^= 1;
  }

  // epilogue: complete l (sum over the 4 g-lanes holding row r), then
  // redistribute to the O layout (lane(g,r) needs l for q rows g*4+reg)
  #pragma unroll
  for (int m = 0; m < 2; ++m) {
    float l = l_lane[m];
    l += __shfl_xor(l, 16);
    l += __shfl_xor(l, 32);                   // all lanes: full l[q=r]
    #pragma unroll
    for (int reg = 0; reg < 4; ++reg) {
      float inv = 1.f / __shfl(l, g * 4 + reg);
      int row = qrow0 + m * 16 + g * 4 + reg;
      #pragma unroll
      for (int n = 0; n < 4; ++n)
        Os[(size_t)row * HD + n * 16 + r] = f2bf(o_acc[m][n][reg] * inv);
    }
  }
}

extern "C" void kernel_launch(void* const* d_in, const int* in_sizes, int n_in,
                              void* d_out, int out_size, void* d_ws, size_t ws_size,
                              hipStream_t stream) {
  const float* x  = (const float*)d_in[0];
  const float* wq = (const float*)d_in[1];
  const float* bq = (const float*)d_in[2];
  const float* wu = (const float*)d_in[3];
  const float* bu = (const float*)d_in[4];
  float* out = (float*)d_out;

  char* ws = (char*)d_ws;
  unsigned short* xb  = (unsigned short*)(ws);                 // 8 MB (reused as vtb)
  unsigned short* qb  = (unsigned short*)(ws + (8u  << 20));   // 8 MB
  unsigned short* ob  = (unsigned short*)(ws + (16u << 20));   // 8 MB (qsb then O)
  unsigned short* wqb = (unsigned short*)(ws + (24u << 20));   // 2 MB
  unsigned short* wub = (unsigned short*)(ws + (26u << 20));   // 2 MB

  cvt_bf16_kernel<<<(NTOK * EMB / 8 + 255) / 256, 256, 0, stream>>>(x, xb, NTOK * EMB);
  cvt_bf16_kernel<<<(EMB * EMB / 8 + 255) / 256, 256, 0, stream>>>(wq, wqb, EMB * EMB);
  cvt_bf16_kernel<<<(EMB * EMB / 8 + 255) / 256, 256, 0, stream>>>(wu, wub, EMB * EMB);

  // q = x @ wq^T + bq -> qb (bf16) and qsb = bf16(q * SEXP2) (single-rounded)
  unsigned short* qsb = ob;   // alias: each attn block reads only its own
                              // q-rows, then writes exactly those rows as O
  gemm_bt_kernel<true><<<dim3(EMB / 128, NTOK / 64), 256, 0, stream>>>(
      xb, wqb, bq, qb, qsb, NTOK, EMB, EMB);

  // xb is dead now; reuse as vtb: per-slab pi-permuted transpose of qb
  unsigned short* vtb = xb;
  transpose_kernel<<<dim3(NS / 64, HEADS * NB), 256, 0, stream>>>(qb, vtb);

  // 512 blocks, slab-grouped XCD swizzle inside the kernel
  attn_kernel<<<dim3(512), 256, 0, stream>>>(qb, qsb, vtb, ob);

  // y = O @ wu^T + bu -> f32
  gemm_bt_kernel<false><<<dim3(EMB / 128, NTOK / 64), 256, 0, stream>>>(
      ob, wub, bu, out, (unsigned short*)nullptr, NTOK, EMB, EMB);
}